// Round 15
// baseline (61.346 us; speedup 1.0000x reference)
//
#include <hip/hip_runtime.h>
#include <hip/hip_bf16.h>

// Problem constants
#define NN 4096
#define CC 64
#define C2 32
#define BB 2

#define M_BLK  32         // m-tile per block
#define KBLK   64         // k per LDS tile
#define KB_ITERS (NN / KBLK)   // NSEG=1: each block covers full k

// Workspace layout (float offsets)
#define WS_Q1 0
#define WS_K1 8192
#define WS_Q2 16384
#define WS_K2 24576
#define WS_V1 32768
#define WS_V2 163840

typedef __attribute__((address_space(1))) const unsigned int GUI;
typedef __attribute__((address_space(3))) unsigned int LUI;
typedef __attribute__((ext_vector_type(8))) short bf16x8;
typedef __attribute__((ext_vector_type(4))) float f32x4;

__device__ __forceinline__ void glds16(const void* g, void* l) {
    __builtin_amdgcn_global_load_lds((GUI*)g, (LUI*)l, 16, 0, 0);
}

__device__ __forceinline__ unsigned short bf16_rne(float f) {
    union { float f; unsigned u; } x; x.f = f;
    unsigned u = x.u + 0x7fff + ((x.u >> 16) & 1);
    return (unsigned short)(u >> 16);
}
// HIP-API packed f32->bf16 RNE (r12-proven)
__device__ __forceinline__ unsigned pack2(float a, float b) {
    __hip_bfloat162 h = __float22bfloat162_rn(make_float2(a, b));
    unsigned r; __builtin_memcpy(&r, &h, 4); return r;
}
__device__ __forceinline__ float sigm_e2(float x) {   // 1/(1+2^x)
    return __builtin_amdgcn_rcpf(1.0f + __builtin_amdgcn_exp2f(x));
}

// ---------------------------------------------------------------------------
// Stage A: 6 projections (byte-identical to r12/r13/r14).
// ---------------------------------------------------------------------------
__global__ __launch_bounds__(256) void proj_kernel(
    const float* __restrict__ x1, const float* __restrict__ x2,
    const float* __restrict__ wq1, const float* __restrict__ bq1,
    const float* __restrict__ wk1, const float* __restrict__ bk1,
    const float* __restrict__ wv1, const float* __restrict__ bv1,
    const float* __restrict__ wq2, const float* __restrict__ bq2,
    const float* __restrict__ wk2, const float* __restrict__ bk2,
    const float* __restrict__ wv2, const float* __restrict__ bv2,
    float* __restrict__ ws)
{
    const int ln = threadIdx.x & 63;
    const int og = threadIdx.x >> 6;
    const int n  = blockIdx.x * 64 + ln;
    const int p  = blockIdx.y;
    const int b  = blockIdx.z;

    const float* x; const float* w; const float* bias;
    int mode; float* dstf; unsigned short* dstv;
    switch (p) {
      case 0: x = x1; w = wq1; bias = bq1; mode = 0; dstf = ws + WS_Q1; dstv = 0; break;
      case 1: x = x1; w = wk1; bias = bk1; mode = 0; dstf = ws + WS_K1; dstv = 0; break;
      case 2: x = x1; w = wv1; bias = bv1; mode = 2; dstf = 0; dstv = (unsigned short*)(ws + WS_V1); break;
      case 3: x = x2; w = wq2; bias = bq2; mode = 1; dstf = ws + WS_Q2; dstv = 0; break;
      case 4: x = x2; w = wk2; bias = bk2; mode = 1; dstf = ws + WS_K2; dstv = 0; break;
      default:x = x2; w = wv2; bias = bv2; mode = 2; dstf = 0; dstv = (unsigned short*)(ws + WS_V2); break;
    }

    __shared__ float red[4][C2][64];

    float acc[C2];
    #pragma unroll
    for (int o = 0; o < C2; ++o) acc[o] = 0.0f;

    const float* xb = x + ((size_t)b * CC + og * 16) * NN + n;
    #pragma unroll
    for (int ci = 0; ci < 16; ++ci) {
        const float xv = xb[(size_t)ci * NN];
        #pragma unroll
        for (int o = 0; o < C2; ++o)
            acc[o] += w[o * CC + og * 16 + ci] * xv;
    }
    #pragma unroll
    for (int o = 0; o < C2; ++o) red[og][o][ln] = acc[o];
    __syncthreads();

    float f[8];
    #pragma unroll
    for (int j = 0; j < 8; ++j) {
        const int o = og * 8 + j;
        f[j] = red[0][o][ln] + red[1][o][ln] + red[2][o][ln] + red[3][o][ln]
             + bias[o];
    }

    if (mode == 2) {
        #pragma unroll
        for (int j = 0; j < 8; ++j)
            dstv[((size_t)b * C2 + og * 8 + j) * NN + n] = bf16_rne(f[j]);
    } else {
        float r;
        if (mode == 0) {
            r = f[0];
            #pragma unroll
            for (int j = 1; j < 8; ++j) r = fmaxf(r, f[j]);
        } else {
            r = 0.0f;
            #pragma unroll
            for (int j = 0; j < 8; ++j) r += f[j];
        }
        __syncthreads();
        red[og][0][ln] = r;
        __syncthreads();
        if (og == 0) {
            const float a0 = red[0][0][ln], a1 = red[1][0][ln];
            const float a2 = red[2][0][ln], a3 = red[3][0][ln];
            const float rr = (mode == 0)
                ? fmaxf(fmaxf(a0, a1), fmaxf(a2, a3))
                : (a0 + a1 + a2 + a3) * (1.0f / C2);
            dstf[(size_t)b * NN + n] = rr;
        }
    }
}

// ---------------------------------------------------------------------------
// Stage B (MFMA, dbuf, 1 barrier/iter, NSEG=1 + FUSED conv epilogue):
// each block covers the FULL k-range for its 32-m tile, so acc is the final
// PV sum; the output 1x1 conv + gamma + residual run in-block and write
// d_out directly. No partials, no conv kernel. Main loop = r14 byte-level.
// Grid 128 x 4 = 512 blocks (2/CU).
// ---------------------------------------------------------------------------
__global__ __launch_bounds__(256) void attn_mfma(
    const float* __restrict__ q1, const float* __restrict__ k1,
    const float* __restrict__ q2, const float* __restrict__ k2,
    const unsigned short* __restrict__ v1, const unsigned short* __restrict__ v2,
    const float* __restrict__ x1,  const float* __restrict__ x2,
    const float* __restrict__ wc1, const float* __restrict__ bc1,
    const float* __restrict__ wc2, const float* __restrict__ bc2,
    const float* __restrict__ g1,  const float* __restrict__ g2,
    float* __restrict__ out)
{
    __shared__ unsigned short vtile[2][C2 * KBLK];     // 2 x 4 KB
    __shared__ unsigned short stile[2][M_BLK * KBLK];  // 2 x 4 KB

    const int tid = threadIdx.x;
    const int wv  = tid >> 6;
    const int ln  = tid & 63;

    const int z      = blockIdx.y;
    const int branch = z & 1;
    const int b      = z >> 1;
    const int m0     = blockIdx.x * M_BLK;

    const float* q; const float* kv; const unsigned short* vbf; float sl2e;
    if (branch == 0) { q = q1; kv = k2; vbf = v1; sl2e =  1.44269504089f; }
    else             { q = q2; kv = k1; vbf = v2; sl2e = -1.44269504089f; }

    const int sm = tid & 31;           // S row (m) this thread computes
    const int sc = tid >> 5;           // k-chunk 0..7 (8 k each)
    const float qs = q[(size_t)b * NN + m0 + sm] * sl2e;
    const float* kvb = kv + (size_t)b * NN;

    f32x4 acc[2];
    #pragma unroll
    for (int mt = 0; mt < 2; ++mt) acc[mt] = (f32x4){0.f, 0.f, 0.f, 0.f};

    const int vc = tid >> 3;           // V c-row 0..31
    const int vs = tid & 7;            // dest slot 0..7
    const unsigned short* vsrc0 = vbf + (size_t)(b * C2 + vc) * NN
                                + ((vs ^ (vc & 7)) << 3);

    auto sigPackWrite = [&](int buf, float4 ka, float4 kb4) {
        float s[8];
        s[0] = sigm_e2(qs * ka.x);  s[1] = sigm_e2(qs * ka.y);
        s[2] = sigm_e2(qs * ka.z);  s[3] = sigm_e2(qs * ka.w);
        s[4] = sigm_e2(qs * kb4.x); s[5] = sigm_e2(qs * kb4.y);
        s[6] = sigm_e2(qs * kb4.z); s[7] = sigm_e2(qs * kb4.w);

        uint4 w;
        w.x = pack2(s[0], s[1]); w.y = pack2(s[2], s[3]);
        w.z = pack2(s[4], s[5]); w.w = pack2(s[6], s[7]);

        char* srow = (char*)stile[buf] + sm * 128;
        *(uint4*)(srow + ((sc ^ (sm & 7)) << 4)) = w;
    };

    // prologue: stage V[0] + compute S[0]
    glds16(vsrc0, (char*)vtile[0] + tid * 16);
    {
        const float* kvp = kvb + sc * 8;
        sigPackWrite(0, *(const float4*)(kvp), *(const float4*)(kvp + 4));
    }
    asm volatile("s_waitcnt vmcnt(0)" ::: "memory");
    __syncthreads();

    const int ct  = wv & 1;
    const int ks  = wv >> 1;
    const int col = (ks << 2) + (ln >> 4);   // slot 0..7
    const int ac  = ct * 16 + (ln & 15);     // V row (c)

    for (int kb = 0; kb < KB_ITERS; ++kb) {
        const int cur = kb & 1;
        const bool more = (kb + 1 < KB_ITERS);

        float4 ka, kb4;
        if (more) {
            glds16(vsrc0 + (kb + 1) * KBLK,
                   (char*)vtile[cur ^ 1] + tid * 16);
            const float* kvp = kvb + (kb + 1) * KBLK + sc * 8;
            ka  = *(const float4*)(kvp);
            kb4 = *(const float4*)(kvp + 4);
        }

        const bf16x8 af = *(const bf16x8*)((const char*)vtile[cur]
                          + ac * 128 + ((col ^ (ac & 7)) << 4));
        #pragma unroll
        for (int mt = 0; mt < 2; ++mt) {
            const int bm = mt * 16 + (ln & 15);
            const bf16x8 bfr = *(const bf16x8*)((const char*)stile[cur]
                               + bm * 128 + ((col ^ (bm & 7)) << 4));
            acc[mt] = __builtin_amdgcn_mfma_f32_16x16x32_bf16(af, bfr, acc[mt], 0, 0, 0);
        }

        if (more) sigPackWrite(cur ^ 1, ka, kb4);

        asm volatile("s_waitcnt vmcnt(0)" ::: "memory");
        __syncthreads();
    }

    // ---- cross-wave k-half reduction -> s_lds[c][m] (32x32 f32) ----
    float* red = (float*)stile;              // 8 KB scratch
    if (wv >= 2) {
        #pragma unroll
        for (int mt = 0; mt < 2; ++mt)
            *(f32x4*)&red[((wv - 2) * 2 + mt) * 256 + ln * 4] = acc[mt];
    }
    __syncthreads();
    float* s_lds = (float*)vtile;            // 4 KB of the 8 KB vtile area
    if (wv < 2) {
        #pragma unroll
        for (int mt = 0; mt < 2; ++mt) {
            const f32x4 o = *(const f32x4*)&red[(wv * 2 + mt) * 256 + ln * 4];
            acc[mt].x += o.x; acc[mt].y += o.y; acc[mt].z += o.z; acc[mt].w += o.w;
            #pragma unroll
            for (int j = 0; j < 4; ++j) {
                const int c = wv * 16 + (ln >> 4) * 4 + j;
                const int m = mt * 16 + (ln & 15);
                s_lds[c * M_BLK + m] = acc[mt][j];
            }
        }
    }
    __syncthreads();

    // ---- fused conv epilogue: thread = (m = tid&31, co-group = tid>>5) ----
    const float* wmat; const float* bias; const float* x; float gamma;
    float* o;
    if (branch == 0) { wmat = wc2; bias = bc2; x = x1; gamma = g1[0]; o = out; }
    else             { wmat = wc1; bias = bc1; x = x2; gamma = g2[0];
                       o = out + (size_t)BB * CC * NN; }

    const int m  = tid & 31;
    const int cg = tid >> 5;                 // 0..7 -> co = cg*8 .. cg*8+7

    float sv[C2];
    #pragma unroll
    for (int c = 0; c < C2; ++c) sv[c] = s_lds[c * M_BLK + m];

    #pragma unroll
    for (int j = 0; j < 8; ++j) {
        const int co = cg * 8 + j;
        float a = bias[co];
        #pragma unroll
        for (int c = 0; c < C2; ++c)
            a += wmat[co * C2 + c] * sv[c];
        const size_t idx = ((size_t)b * CC + co) * NN + m0 + m;
        o[idx] = x[idx] + gamma * a;
    }
}

extern "C" void kernel_launch(void* const* d_in, const int* in_sizes, int n_in,
                              void* d_out, int out_size, void* d_ws, size_t ws_size,
                              hipStream_t stream)
{
    const float* x1  = (const float*)d_in[0];
    const float* x2  = (const float*)d_in[1];
    const float* wq1 = (const float*)d_in[2];
    const float* bq1 = (const float*)d_in[3];
    const float* wk1 = (const float*)d_in[4];
    const float* bk1 = (const float*)d_in[5];
    const float* wv1 = (const float*)d_in[6];
    const float* bv1 = (const float*)d_in[7];
    const float* wc1 = (const float*)d_in[8];
    const float* bc1 = (const float*)d_in[9];
    const float* wq2 = (const float*)d_in[10];
    const float* bq2 = (const float*)d_in[11];
    const float* wk2 = (const float*)d_in[12];
    const float* bk2 = (const float*)d_in[13];
    const float* wv2 = (const float*)d_in[14];
    const float* bv2 = (const float*)d_in[15];
    const float* wc2 = (const float*)d_in[16];
    const float* bc2 = (const float*)d_in[17];
    const float* g1  = (const float*)d_in[18];
    const float* g2  = (const float*)d_in[19];

    float* ws  = (float*)d_ws;
    float* out = (float*)d_out;

    proj_kernel<<<dim3(NN / 64, 6, BB), 256, 0, stream>>>(
        x1, x2, wq1, bq1, wk1, bk1, wv1, bv1,
        wq2, bq2, wk2, bk2, wv2, bv2, ws);

    const float* q1 = ws + WS_Q1; const float* k1 = ws + WS_K1;
    const float* q2 = ws + WS_Q2; const float* k2 = ws + WS_K2;
    const unsigned short* v1 = (const unsigned short*)(ws + WS_V1);
    const unsigned short* v2 = (const unsigned short*)(ws + WS_V2);

    attn_mfma<<<dim3(NN / M_BLK, BB * 2), 256, 0, stream>>>(
        q1, k1, q2, k2, v1, v2,
        x1, x2, wc1, bc1, wc2, bc2, g1, g2, out);
}

// Round 16
// 57.902 us; speedup vs baseline: 1.0595x; 1.0595x over previous
//
#include <hip/hip_runtime.h>
#include <hip/hip_bf16.h>

// Problem constants
#define NN 4096
#define CC 64
#define C2 32
#define BB 2

#define M_BLK  16         // m-tile per block (r16: 32 -> 16 to restore 4 blocks/CU)
#define KBLK   64         // k per LDS tile
#define KB_ITERS (NN / KBLK)   // NSEG=1: each block covers full k

// Workspace layout (float offsets)
#define WS_Q1 0
#define WS_K1 8192
#define WS_Q2 16384
#define WS_K2 24576
#define WS_V1 32768
#define WS_V2 163840

typedef __attribute__((address_space(1))) const unsigned int GUI;
typedef __attribute__((address_space(3))) unsigned int LUI;
typedef __attribute__((ext_vector_type(8))) short bf16x8;
typedef __attribute__((ext_vector_type(4))) float f32x4;

__device__ __forceinline__ void glds16(const void* g, void* l) {
    __builtin_amdgcn_global_load_lds((GUI*)g, (LUI*)l, 16, 0, 0);
}

__device__ __forceinline__ unsigned short bf16_rne(float f) {
    union { float f; unsigned u; } x; x.f = f;
    unsigned u = x.u + 0x7fff + ((x.u >> 16) & 1);
    return (unsigned short)(u >> 16);
}
// HIP-API packed f32->bf16 RNE (r12-proven)
__device__ __forceinline__ unsigned pack2(float a, float b) {
    __hip_bfloat162 h = __float22bfloat162_rn(make_float2(a, b));
    unsigned r; __builtin_memcpy(&r, &h, 4); return r;
}
__device__ __forceinline__ float sigm_e2(float x) {   // 1/(1+2^x)
    return __builtin_amdgcn_rcpf(1.0f + __builtin_amdgcn_exp2f(x));
}

// ---------------------------------------------------------------------------
// Stage A: 6 projections (byte-identical to r12-r15).
// ---------------------------------------------------------------------------
__global__ __launch_bounds__(256) void proj_kernel(
    const float* __restrict__ x1, const float* __restrict__ x2,
    const float* __restrict__ wq1, const float* __restrict__ bq1,
    const float* __restrict__ wk1, const float* __restrict__ bk1,
    const float* __restrict__ wv1, const float* __restrict__ bv1,
    const float* __restrict__ wq2, const float* __restrict__ bq2,
    const float* __restrict__ wk2, const float* __restrict__ bk2,
    const float* __restrict__ wv2, const float* __restrict__ bv2,
    float* __restrict__ ws)
{
    const int ln = threadIdx.x & 63;
    const int og = threadIdx.x >> 6;
    const int n  = blockIdx.x * 64 + ln;
    const int p  = blockIdx.y;
    const int b  = blockIdx.z;

    const float* x; const float* w; const float* bias;
    int mode; float* dstf; unsigned short* dstv;
    switch (p) {
      case 0: x = x1; w = wq1; bias = bq1; mode = 0; dstf = ws + WS_Q1; dstv = 0; break;
      case 1: x = x1; w = wk1; bias = bk1; mode = 0; dstf = ws + WS_K1; dstv = 0; break;
      case 2: x = x1; w = wv1; bias = bv1; mode = 2; dstf = 0; dstv = (unsigned short*)(ws + WS_V1); break;
      case 3: x = x2; w = wq2; bias = bq2; mode = 1; dstf = ws + WS_Q2; dstv = 0; break;
      case 4: x = x2; w = wk2; bias = bk2; mode = 1; dstf = ws + WS_K2; dstv = 0; break;
      default:x = x2; w = wv2; bias = bv2; mode = 2; dstf = 0; dstv = (unsigned short*)(ws + WS_V2); break;
    }

    __shared__ float red[4][C2][64];

    float acc[C2];
    #pragma unroll
    for (int o = 0; o < C2; ++o) acc[o] = 0.0f;

    const float* xb = x + ((size_t)b * CC + og * 16) * NN + n;
    #pragma unroll
    for (int ci = 0; ci < 16; ++ci) {
        const float xv = xb[(size_t)ci * NN];
        #pragma unroll
        for (int o = 0; o < C2; ++o)
            acc[o] += w[o * CC + og * 16 + ci] * xv;
    }
    #pragma unroll
    for (int o = 0; o < C2; ++o) red[og][o][ln] = acc[o];
    __syncthreads();

    float f[8];
    #pragma unroll
    for (int j = 0; j < 8; ++j) {
        const int o = og * 8 + j;
        f[j] = red[0][o][ln] + red[1][o][ln] + red[2][o][ln] + red[3][o][ln]
             + bias[o];
    }

    if (mode == 2) {
        #pragma unroll
        for (int j = 0; j < 8; ++j)
            dstv[((size_t)b * C2 + og * 8 + j) * NN + n] = bf16_rne(f[j]);
    } else {
        float r;
        if (mode == 0) {
            r = f[0];
            #pragma unroll
            for (int j = 1; j < 8; ++j) r = fmaxf(r, f[j]);
        } else {
            r = 0.0f;
            #pragma unroll
            for (int j = 0; j < 8; ++j) r += f[j];
        }
        __syncthreads();
        red[og][0][ln] = r;
        __syncthreads();
        if (og == 0) {
            const float a0 = red[0][0][ln], a1 = red[1][0][ln];
            const float a2 = red[2][0][ln], a3 = red[3][0][ln];
            const float rr = (mode == 0)
                ? fmaxf(fmaxf(a0, a1), fmaxf(a2, a3))
                : (a0 + a1 + a2 + a3) * (1.0f / C2);
            dstf[(size_t)b * NN + n] = rr;
        }
    }
}

// ---------------------------------------------------------------------------
// Stage B (MFMA, dbuf, 1 barrier/iter, NSEG=1, fused conv epilogue,
// M_BLK=16): grid 256 x 4 = 1024 blocks = 4 blocks/CU (r15's 2/CU exposed
// the iter chain: VALUBusy 28.6%). Thread S-duty: (m = tid&15,
// k-chunk = tid>>4): 4 sigmoids + 1 uint2 ds_write. Wave MFMA duty:
// (ct = wv&1, ks = wv>>1): 1 MFMA/iter, acc = 1 f32x4.
// S swizzle: 8B granule inside the same 16B-slot XOR as the b128 read.
// ---------------------------------------------------------------------------
__global__ __launch_bounds__(256) void attn_mfma(
    const float* __restrict__ q1, const float* __restrict__ k1,
    const float* __restrict__ q2, const float* __restrict__ k2,
    const unsigned short* __restrict__ v1, const unsigned short* __restrict__ v2,
    const float* __restrict__ x1,  const float* __restrict__ x2,
    const float* __restrict__ wc1, const float* __restrict__ bc1,
    const float* __restrict__ wc2, const float* __restrict__ bc2,
    const float* __restrict__ g1,  const float* __restrict__ g2,
    float* __restrict__ out)
{
    __shared__ unsigned short vtile[2][C2 * KBLK];     // 2 x 4 KB
    __shared__ unsigned short stile[2][M_BLK * KBLK];  // 2 x 2 KB

    const int tid = threadIdx.x;
    const int wv  = tid >> 6;
    const int ln  = tid & 63;

    const int z      = blockIdx.y;
    const int branch = z & 1;
    const int b      = z >> 1;
    const int m0     = blockIdx.x * M_BLK;

    const float* q; const float* kv; const unsigned short* vbf; float sl2e;
    if (branch == 0) { q = q1; kv = k2; vbf = v1; sl2e =  1.44269504089f; }
    else             { q = q2; kv = k1; vbf = v2; sl2e = -1.44269504089f; }

    const int sm = tid & 15;           // S row (m) this thread computes
    const int sc = tid >> 4;           // k-chunk 0..15 (4 k each)
    const float qs = q[(size_t)b * NN + m0 + sm] * sl2e;
    const float* kvb = kv + (size_t)b * NN;

    f32x4 acc = (f32x4){0.f, 0.f, 0.f, 0.f};

    const int vc = tid >> 3;           // V c-row 0..31
    const int vs = tid & 7;            // dest slot 0..7
    const unsigned short* vsrc0 = vbf + (size_t)(b * C2 + vc) * NN
                                + ((vs ^ (vc & 7)) << 3);

    // sigmoid + pack + swizzled 8B ds_write of this thread's 4-k chunk
    auto sigPackWrite = [&](int buf, float4 ka) {
        float s[4];
        s[0] = sigm_e2(qs * ka.x);  s[1] = sigm_e2(qs * ka.y);
        s[2] = sigm_e2(qs * ka.z);  s[3] = sigm_e2(qs * ka.w);

        uint2 w;
        w.x = pack2(s[0], s[1]); w.y = pack2(s[2], s[3]);

        char* srow = (char*)stile[buf] + sm * 128;
        *(uint2*)(srow + ((((sc >> 1) ^ (sm & 7)) << 4) + ((sc & 1) << 3))) = w;
    };

    // prologue: stage V[0] + compute S[0]
    glds16(vsrc0, (char*)vtile[0] + tid * 16);
    sigPackWrite(0, *(const float4*)(kvb + sc * 4));
    asm volatile("s_waitcnt vmcnt(0)" ::: "memory");
    __syncthreads();

    const int ct  = wv & 1;
    const int ks  = wv >> 1;
    const int col = (ks << 2) + (ln >> 4);   // slot 0..7
    const int ac  = ct * 16 + (ln & 15);     // V row (c)
    const int bm  = ln & 15;                 // S row (m)

    for (int kb = 0; kb < KB_ITERS; ++kb) {
        const int cur = kb & 1;
        const bool more = (kb + 1 < KB_ITERS);

        float4 ka;
        if (more) {
            glds16(vsrc0 + (kb + 1) * KBLK,
                   (char*)vtile[cur ^ 1] + tid * 16);
            ka = *(const float4*)(kvb + (kb + 1) * KBLK + sc * 4);
        }

        const bf16x8 af = *(const bf16x8*)((const char*)vtile[cur]
                          + ac * 128 + ((col ^ (ac & 7)) << 4));
        const bf16x8 bfr = *(const bf16x8*)((const char*)stile[cur]
                           + bm * 128 + ((col ^ (bm & 7)) << 4));
        acc = __builtin_amdgcn_mfma_f32_16x16x32_bf16(af, bfr, acc, 0, 0, 0);

        if (more) sigPackWrite(cur ^ 1, ka);

        asm volatile("s_waitcnt vmcnt(0)" ::: "memory");
        __syncthreads();
    }

    // ---- cross-wave k-half reduction -> s_lds[c][m] (32c x 16m f32) ----
    float* red = (float*)stile;              // 4 KB scratch (need 2 KB)
    if (wv >= 2)
        *(f32x4*)&red[(wv - 2) * 256 + ln * 4] = acc;
    __syncthreads();
    float* s_lds = (float*)vtile;            // 2 KB of the 8 KB vtile area
    if (wv < 2) {
        const f32x4 o = *(const f32x4*)&red[wv * 256 + ln * 4];
        acc.x += o.x; acc.y += o.y; acc.z += o.z; acc.w += o.w;
        #pragma unroll
        for (int j = 0; j < 4; ++j) {
            const int c = wv * 16 + (ln >> 4) * 4 + j;
            s_lds[c * M_BLK + (ln & 15)] = acc[j];
        }
    }
    __syncthreads();

    // ---- fused conv epilogue: thread = (m = tid&15, co-grp = tid>>4) ----
    const float* wmat; const float* bias; const float* x; float gamma;
    float* o;
    if (branch == 0) { wmat = wc2; bias = bc2; x = x1; gamma = g1[0]; o = out; }
    else             { wmat = wc1; bias = bc1; x = x2; gamma = g2[0];
                       o = out + (size_t)BB * CC * NN; }

    const int m  = tid & 15;
    const int ch = tid >> 4;                 // 0..15 -> co = ch*4 .. ch*4+3

    float sv[C2];
    #pragma unroll
    for (int c = 0; c < C2; ++c) sv[c] = s_lds[c * M_BLK + m];

    #pragma unroll
    for (int j = 0; j < 4; ++j) {
        const int co = ch * 4 + j;
        float a = bias[co];
        #pragma unroll
        for (int c = 0; c < C2; ++c)
            a += wmat[co * C2 + c] * sv[c];
        const size_t idx = ((size_t)b * CC + co) * NN + m0 + m;
        o[idx] = x[idx] + gamma * a;
    }
}

extern "C" void kernel_launch(void* const* d_in, const int* in_sizes, int n_in,
                              void* d_out, int out_size, void* d_ws, size_t ws_size,
                              hipStream_t stream)
{
    const float* x1  = (const float*)d_in[0];
    const float* x2  = (const float*)d_in[1];
    const float* wq1 = (const float*)d_in[2];
    const float* bq1 = (const float*)d_in[3];
    const float* wk1 = (const float*)d_in[4];
    const float* bk1 = (const float*)d_in[5];
    const float* wv1 = (const float*)d_in[6];
    const float* bv1 = (const float*)d_in[7];
    const float* wc1 = (const float*)d_in[8];
    const float* bc1 = (const float*)d_in[9];
    const float* wq2 = (const float*)d_in[10];
    const float* bq2 = (const float*)d_in[11];
    const float* wk2 = (const float*)d_in[12];
    const float* bk2 = (const float*)d_in[13];
    const float* wv2 = (const float*)d_in[14];
    const float* bv2 = (const float*)d_in[15];
    const float* wc2 = (const float*)d_in[16];
    const float* bc2 = (const float*)d_in[17];
    const float* g1  = (const float*)d_in[18];
    const float* g2  = (const float*)d_in[19];

    float* ws  = (float*)d_ws;
    float* out = (float*)d_out;

    proj_kernel<<<dim3(NN / 64, 6, BB), 256, 0, stream>>>(
        x1, x2, wq1, bq1, wk1, bk1, wv1, bv1,
        wq2, bq2, wk2, bk2, wv2, bv2, ws);

    const float* q1 = ws + WS_Q1; const float* k1 = ws + WS_K1;
    const float* q2 = ws + WS_Q2; const float* k2 = ws + WS_K2;
    const unsigned short* v1 = (const unsigned short*)(ws + WS_V1);
    const unsigned short* v2 = (const unsigned short*)(ws + WS_V2);

    attn_mfma<<<dim3(NN / M_BLK, BB * 2), 256, 0, stream>>>(
        q1, k1, q2, k2, v1, v2,
        x1, x2, wc1, bc1, wc2, bc2, g1, g2, out);
}